// Round 2
// baseline (807.819 us; speedup 1.0000x reference)
//
#include <hip/hip_runtime.h>

// LIF neuron: v_t = ALPHA*v_{t-1} + (x_t . w) - V_TH*z_{t-1}; z_t = 1[v_t > V_TH]
// x: [B=128, T=1000, N=1024] fp32, w: [N] fp32.
// Out: v_seq [B,T] ++ z_seq [B,T], flat fp32.

#define ALPHA 0.995f
#define V_TH 2.0f

constexpr int B = 128;
constexpr int T = 1000;
constexpr int N = 1024;

// ---------------------------------------------------------------------------
// Kernel 1: drive_t[t*B + b] = dot(x[row,:], w), row = b*T + t.
// 2000 blocks x 4 waves; each wave owns 16 consecutive rows (64 KB stream).
// w preloaded into 16 VGPRs once per wave (kills the redundant 524 MB w
// re-load of R1). Two rows in flight per iteration: 8 KB of loads issued
// before any dependent use; 8 independent fp64 partial chains; the two
// 6-step shuffle-reduce chains interleave so their latency overlaps.
// ---------------------------------------------------------------------------
__global__ __launch_bounds__(256) void lif_dot_kernel(
    const float* __restrict__ x, const float* __restrict__ w,
    float* __restrict__ drive_t) {
    const int lane = threadIdx.x & 63;
    const int gwave = blockIdx.x * 4 + (threadIdx.x >> 6);  // 0..7999
    const int base_row = gwave * 16;                        // 16 rows/wave

    const float* wp = w + lane * 4;
    const float4 w0 = *(const float4*)(wp);
    const float4 w1 = *(const float4*)(wp + 256);
    const float4 w2 = *(const float4*)(wp + 512);
    const float4 w3 = *(const float4*)(wp + 768);

    for (int i = 0; i < 16; i += 2) {
        const float* xr0 = x + (long long)(base_row + i) * N + lane * 4;
        const float* xr1 = xr0 + N;
        // issue all 8 loads (8 KB/wave in flight) before any use
        const float4 a0 = *(const float4*)(xr0);
        const float4 a1 = *(const float4*)(xr0 + 256);
        const float4 a2 = *(const float4*)(xr0 + 512);
        const float4 a3 = *(const float4*)(xr0 + 768);
        const float4 b0 = *(const float4*)(xr1);
        const float4 b1 = *(const float4*)(xr1 + 256);
        const float4 b2 = *(const float4*)(xr1 + 512);
        const float4 b3 = *(const float4*)(xr1 + 768);

        // 8 independent 4-deep fp64 chains (vs one 16-deep chain in R1)
        double s0 = (double)a0.x*w0.x + (double)a0.y*w0.y + (double)a0.z*w0.z + (double)a0.w*w0.w;
        double s1 = (double)a1.x*w1.x + (double)a1.y*w1.y + (double)a1.z*w1.z + (double)a1.w*w1.w;
        double s2 = (double)a2.x*w2.x + (double)a2.y*w2.y + (double)a2.z*w2.z + (double)a2.w*w2.w;
        double s3 = (double)a3.x*w3.x + (double)a3.y*w3.y + (double)a3.z*w3.z + (double)a3.w*w3.w;
        double t0 = (double)b0.x*w0.x + (double)b0.y*w0.y + (double)b0.z*w0.z + (double)b0.w*w0.w;
        double t1 = (double)b1.x*w1.x + (double)b1.y*w1.y + (double)b1.z*w1.z + (double)b1.w*w1.w;
        double t2 = (double)b2.x*w2.x + (double)b2.y*w2.y + (double)b2.z*w2.z + (double)b2.w*w2.w;
        double t3 = (double)b3.x*w3.x + (double)b3.y*w3.y + (double)b3.z*w3.z + (double)b3.w*w3.w;
        double accA = (s0 + s1) + (s2 + s3);
        double accB = (t0 + t1) + (t2 + t3);

        // interleaved butterfly reductions (two independent chains)
#pragma unroll
        for (int off = 32; off >= 1; off >>= 1) {
            accA += __shfl_down(accA, off);
            accB += __shfl_down(accB, off);
        }

        if (lane == 0) {
            const int row = base_row + i;
            const int b = row / T;
            const int t = row - b * T;
            drive_t[t * B + b] = (float)accA;          // row
            // row+1: t+1 may wrap into next b only if t==T-1; rows within a
            // wave's chunk of 16 stay inside one b iff base_row%T+16<=T.
            const int row2 = row + 1;
            const int b2 = row2 / T;
            const int t2 = row2 - b2 * T;
            drive_t[t2 * B + b2] = (float)accB;
        }
    }
}

// ---------------------------------------------------------------------------
// Kernel 2: sequential LIF scan. 2 blocks x 256 threads; block handles 64
// batch rows. Per 50-step tile: (0) all 256 threads load the drive tile
// LDS-coalesced, (A) 64 scan threads run the recurrence writing v/z into
// padded LDS, (B) all 256 threads store v/z tiles to global coalesced
// (fixes R1's 64-cacheline-spray stores).
// ---------------------------------------------------------------------------
__global__ __launch_bounds__(256) void lif_scan_kernel(
    const float* __restrict__ drive_t, float* __restrict__ out) {
    constexpr int TT = 50;   // 20 tiles of 50 steps
    constexpr int BB = 64;   // batches per block
    __shared__ float s_drive[TT][BB];      // 12.8 KB
    __shared__ float s_v[BB][TT + 1];      // padded: stride 51 -> conflict-free
    __shared__ float s_z[BB][TT + 1];

    const int tid = threadIdx.x;
    const int b0 = blockIdx.x * BB;
    const int jload = tid >> 6;            // 0..3
    const int bload = tid & 63;

    float v = 0.0f, z = 0.0f;

    for (int t0 = 0; t0 < T; t0 += TT) {
        // Phase 0: drive tile -> LDS (coalesced: lanes span b)
        for (int j = jload; j < TT; j += 4)
            s_drive[j][bload] = drive_t[(t0 + j) * B + b0 + bload];
        __syncthreads();

        // Phase A: 64 scan threads, 50 serial steps
        if (tid < BB) {
#pragma unroll
            for (int j = 0; j < TT; ++j) {
                const float d = s_drive[j][tid];
                v = ALPHA * v + d - V_TH * z;
                z = (v - V_TH > 0.0f) ? 1.0f : 0.0f;
                s_v[tid][j] = v;
                s_z[tid][j] = z;
            }
        }
        __syncthreads();

        // Phase B: coalesced stores (consecutive threads -> consecutive t)
        for (int idx = tid; idx < BB * TT; idx += 256) {
            const int bb = idx / TT;
            const int j = idx - bb * TT;
            out[(long long)(b0 + bb) * T + t0 + j] = s_v[bb][j];
        }
        for (int idx = tid; idx < BB * TT; idx += 256) {
            const int bb = idx / TT;
            const int j = idx - bb * TT;
            out[(long long)B * T + (long long)(b0 + bb) * T + t0 + j] = s_z[bb][j];
        }
        // no barrier needed here: next Phase0 touches only s_drive (not read
        // after Phase A), and next Phase A starts only after the Phase0
        // barrier, which orders it after this Phase B's s_v/s_z reads.
    }
}

extern "C" void kernel_launch(void* const* d_in, const int* in_sizes, int n_in,
                              void* d_out, int out_size, void* d_ws, size_t ws_size,
                              hipStream_t stream) {
    const float* x = (const float*)d_in[0];   // [B,T,N]
    const float* w = (const float*)d_in[1];   // [N]
    float* out = (float*)d_out;               // v[B,T] ++ z[B,T]
    float* drive_t = (float*)d_ws;            // [T,B] scratch, 512 KB

    // 8000 waves x 16 rows = 128000 rows
    lif_dot_kernel<<<2000, 256, 0, stream>>>(x, w, drive_t);
    lif_scan_kernel<<<2, 256, 0, stream>>>(drive_t, out);
}

// Round 3
// 686.522 us; speedup vs baseline: 1.1767x; 1.1767x over previous
//
#include <hip/hip_runtime.h>

// LIF neuron: v_t = ALPHA*v_{t-1} + (x_t . w) - V_TH*z_{t-1}; z_t = 1[v_t > V_TH]
// x: [B=128, T=1000, N=1024] fp32, w: [N] fp32.
// Out: v_seq [B,T] ++ z_seq [B,T], flat fp32.
//
// NOTE (R2 post-mortem): dur_us appears to include the harness's per-iteration
// restore (~490 us: 2 GB ws poison + 524 MB d_in restore). Our kernels' floor
// is x-read 524 MB / 6.3 TB/s ~= 83 us.

#define ALPHA 0.995f
#define V_TH 2.0f

constexpr int B = 128;
constexpr int T = 1000;
constexpr int N = 1024;

typedef float f32x4 __attribute__((ext_vector_type(4)));

// ---------------------------------------------------------------------------
// Kernel 1: drive_t[t*B + b] = dot(x[row,:], w), row = b*T + t.
// 8000 blocks x 4 waves; each wave owns 4 rows, processed as a 2-row
// software pipeline (8 KB of loads in flight, 8 independent 4-deep fp64
// chains, two interleaved shuffle-reduce chains). 32000 waves queued deep
// (~31/SIMD) so the per-row reduce latency hides — R2's regression was 16
// rows/wave at ~4 resident waves/SIMD with exposed reduce chains.
// ---------------------------------------------------------------------------
__global__ __launch_bounds__(256) void lif_dot_kernel(
    const float* __restrict__ x, const float* __restrict__ w,
    float* __restrict__ drive_t) {
    const int lane = threadIdx.x & 63;
    const int gwave = blockIdx.x * 4 + (threadIdx.x >> 6);  // 0..31999
    const int base_row = gwave * 4;                         // 4 rows/wave

    const float* wp = w + lane * 4;
    const f32x4 w0 = *(const f32x4*)(wp);
    const f32x4 w1 = *(const f32x4*)(wp + 256);
    const f32x4 w2 = *(const f32x4*)(wp + 512);
    const f32x4 w3 = *(const f32x4*)(wp + 768);

#pragma unroll
    for (int i = 0; i < 4; i += 2) {
        const f32x4* xr0 = (const f32x4*)(x + (long long)(base_row + i) * N + lane * 4);
        const f32x4* xr1 = (const f32x4*)((const float*)xr0 + N);
        // issue all 8 loads (8 KB/wave) before any use; nontemporal: x is
        // streamed once, keep it from thrashing L2
        const f32x4 a0 = __builtin_nontemporal_load(xr0);
        const f32x4 a1 = __builtin_nontemporal_load(xr0 + 64);
        const f32x4 a2 = __builtin_nontemporal_load(xr0 + 128);
        const f32x4 a3 = __builtin_nontemporal_load(xr0 + 192);
        const f32x4 b0 = __builtin_nontemporal_load(xr1);
        const f32x4 b1 = __builtin_nontemporal_load(xr1 + 64);
        const f32x4 b2 = __builtin_nontemporal_load(xr1 + 128);
        const f32x4 b3 = __builtin_nontemporal_load(xr1 + 192);

        // 8 independent 4-deep fp64 chains
        double s0 = (double)a0.x*w0.x + (double)a0.y*w0.y + (double)a0.z*w0.z + (double)a0.w*w0.w;
        double s1 = (double)a1.x*w1.x + (double)a1.y*w1.y + (double)a1.z*w1.z + (double)a1.w*w1.w;
        double s2 = (double)a2.x*w2.x + (double)a2.y*w2.y + (double)a2.z*w2.z + (double)a2.w*w2.w;
        double s3 = (double)a3.x*w3.x + (double)a3.y*w3.y + (double)a3.z*w3.z + (double)a3.w*w3.w;
        double t0 = (double)b0.x*w0.x + (double)b0.y*w0.y + (double)b0.z*w0.z + (double)b0.w*w0.w;
        double t1 = (double)b1.x*w1.x + (double)b1.y*w1.y + (double)b1.z*w1.z + (double)b1.w*w1.w;
        double t2 = (double)b2.x*w2.x + (double)b2.y*w2.y + (double)b2.z*w2.z + (double)b2.w*w2.w;
        double t3 = (double)b3.x*w3.x + (double)b3.y*w3.y + (double)b3.z*w3.z + (double)b3.w*w3.w;
        double accA = (s0 + s1) + (s2 + s3);
        double accB = (t0 + t1) + (t2 + t3);

        // two interleaved butterfly reductions (latencies overlap)
#pragma unroll
        for (int off = 32; off >= 1; off >>= 1) {
            accA += __shfl_down(accA, off);
            accB += __shfl_down(accB, off);
        }

        if (lane == 0) {
            const int row = base_row + i;
            const int b1_ = row / T;
            const int t1_ = row - b1_ * T;
            drive_t[t1_ * B + b1_] = (float)accA;
            const int row2 = row + 1;
            const int b2_ = row2 / T;
            const int t2_ = row2 - b2_ * T;
            drive_t[t2_ * B + b2_] = (float)accB;
        }
    }
}

// ---------------------------------------------------------------------------
// Kernel 2: sequential LIF scan. ONE block x 512 threads covering all 128
// batch rows, tiles of TT=64 timesteps (last tile 40):
//   P0: drive tile [64][128] is CONTIGUOUS in global ([T,B] layout) ->
//       float4-coalesced loads into LDS.
//   PA: threads 0..127 (2 waves) run 64 serial recurrence steps; v/z into
//       stride-65-padded LDS (65%32==1 -> conflict-free).
//   PB: all 512 threads store v and z tiles as aligned float4 (T=1000 and
//       t0,j multiples of 4 -> 16B-aligned addresses).
// ~16 tiles x ~2k cyc ~= 15 us.
// ---------------------------------------------------------------------------
__global__ __launch_bounds__(512) void lif_scan_kernel(
    const float* __restrict__ drive_t, float* __restrict__ out) {
    __shared__ float s_drive[64 * B];      // [j][b], 32 KB
    __shared__ float s_v[B][65];           // padded -> conflict-free
    __shared__ float s_z[B][65];
    const int tid = threadIdx.x;

    float v = 0.0f, z = 0.0f;
    for (int t0 = 0; t0 < T; t0 += 64) {
        const int TT = (T - t0 < 64) ? (T - t0) : 64;   // 64 or 40
        const int nq = (TT * B) / 4;                    // float4 count

        // P0: coalesced tile load
        const f32x4* src = (const f32x4*)(drive_t + t0 * B);
        f32x4* dst = (f32x4*)s_drive;
        for (int idx = tid; idx < nq; idx += 512)
            dst[idx] = src[idx];
        __syncthreads();

        // PA: serial scan, one thread per batch row
        if (tid < B) {
            float vv = v, zz = z;
            for (int j = 0; j < TT; ++j) {
                const float d = s_drive[j * B + tid];
                vv = ALPHA * vv + d - V_TH * zz;
                zz = (vv - V_TH > 0.0f) ? 1.0f : 0.0f;
                s_v[tid][j] = vv;
                s_z[tid][j] = zz;
            }
            v = vv; z = zz;
        }
        __syncthreads();

        // PB: aligned float4 stores (TT%4==0, T%4==0, t0%4==0)
        const int qpb = TT / 4;                         // quads per row
        for (int idx = tid; idx < nq; idx += 512) {
            const int bb = idx / qpb;
            const int j4 = (idx - bb * qpb) * 4;
            f32x4 vq = { s_v[bb][j4], s_v[bb][j4+1], s_v[bb][j4+2], s_v[bb][j4+3] };
            *(f32x4*)(out + (long long)bb * T + t0 + j4) = vq;
            f32x4 zq = { s_z[bb][j4], s_z[bb][j4+1], s_z[bb][j4+2], s_z[bb][j4+3] };
            *(f32x4*)(out + (long long)(B + bb) * T + t0 + j4) = zq;
        }
        __syncthreads();   // s_drive/s_v/s_z reuse next tile
    }
}

extern "C" void kernel_launch(void* const* d_in, const int* in_sizes, int n_in,
                              void* d_out, int out_size, void* d_ws, size_t ws_size,
                              hipStream_t stream) {
    const float* x = (const float*)d_in[0];   // [B,T,N]
    const float* w = (const float*)d_in[1];   // [N]
    float* out = (float*)d_out;               // v[B,T] ++ z[B,T]
    float* drive_t = (float*)d_ws;            // [T,B] scratch, 512 KB

    // 32000 waves x 4 rows = 128000 rows
    lif_dot_kernel<<<8000, 256, 0, stream>>>(x, w, drive_t);
    lif_scan_kernel<<<1, 512, 0, stream>>>(drive_t, out);
}